// Round 15
// baseline (251.304 us; speedup 1.0000x reference)
//
#include <hip/hip_runtime.h>

#define SEQ_T   2048
#define BATCH_N 4096
#define LOG2E   1.4426950408889634f
#define K_SEG   16
#define NSEG    (SEQ_T / K_SEG)   // 128 segments

// Pipelined LSTM cell step, hand-scheduled, DPP-fused operands.
// Computes cell(acc(t)) AND the input dot for step t+1 (accn) in the
// trans/DPP wait slots. 16-lane chain group, UNIT-MAJOR lane = 4u + r.
// Hazard audit (validated R13->R14):
//  (a) trans write -> consumer: 1 wait. Gate chain: filled by accn FMAs;
//      tanh chain: s_nop 0 (nothing independent left).
//  (b) VALU write -> DPP read of same VGPR: 2 waits. a->quad_perm: filled by
//      2 accn FMAs. h seam (prev cell's final v_mul): entry s_nop 3 + fmac.
//  (c) SALU EXEC write -> DPP: 5 waits. Entry gap covers (store's exec
//      restore + caller instrs + fmac + s_nop 3 >= 5).
//  accn FMAs never touch t/a/h/cs -> no new hazards.
__device__ __forceinline__ void cell_pipe(float& acc, float& accn,
                                          float& h, float& cs,
                                          float w0, float w1, float w2, float w3,
                                          float wn0, float wn1, float wn2, float wn3,
                                          float i0, float i1, float i2, float i3,
                                          float bbn, float ka, float kb) {
    float t, a, gv, cn, hn;
    asm("v_fmac_f32 %[acc], %[h], %[w0]\n\t"            // plain h (interlocked)
        "s_nop 3\n\t"                                   // (b)/(c) h DPP reads
        "v_fmac_f32 %[acc], %[h], %[w1] row_half_mirror row_mask:0xf bank_mask:0xf\n\t"
        "v_fmac_f32 %[acc], %[h], %[w2] row_ror:8 row_mask:0xf bank_mask:0xf\n\t"
        "v_fmac_f32 %[acc], %[h], %[w3] row_mirror row_mask:0xf bank_mask:0xf\n\t"
        "v_exp_f32 %[t], %[acc]\n\t"
        "v_fma_f32 %[an], %[wn0], %[i0], %[bbn]\n\t"    // fill (a)
        "v_add_f32 %[t], 1.0, %[t]\n\t"
        "v_rcp_f32 %[t], %[t]\n\t"
        "v_fmac_f32 %[an], %[wn1], %[i1]\n\t"           // fill (a)
        "v_fma_f32 %[a], %[ka], %[t], %[kb]\n\t"
        "v_fmac_f32 %[an], %[wn2], %[i2]\n\t"           // fill (b) 1/2
        "v_fmac_f32 %[an], %[wn3], %[i3]\n\t"           // fill (b) 2/2
        "v_mov_b32 %[gv], %[a] quad_perm:[2,2,2,2] row_mask:0xf bank_mask:0xf\n\t"
        "v_mul_f32 %[cn], %[a], %[gv] quad_perm:[0,0,0,0] row_mask:0xf bank_mask:0xf\n\t"
        "v_fmac_f32 %[cn], %[a], %[cs] quad_perm:[1,1,1,1] row_mask:0xf bank_mask:0xf\n\t"
        "v_exp_f32 %[t], %[cn]\n\t"
        "s_nop 0\n\t"                                   // (a)
        "v_add_f32 %[t], 1.0, %[t]\n\t"
        "v_rcp_f32 %[t], %[t]\n\t"
        "s_nop 0\n\t"                                   // (a)
        "v_fma_f32 %[hn], 2.0, %[t], -1.0\n\t"
        "v_mul_f32 %[h], %[a], %[hn] quad_perm:[3,3,3,3] row_mask:0xf bank_mask:0xf\n\t"
        : [acc] "+v"(acc), [h] "+v"(h), [an] "=&v"(accn),
          [t] "=&v"(t), [a] "=&v"(a), [gv] "=&v"(gv),
          [cn] "=&v"(cn), [hn] "=&v"(hn)
        : [cs] "v"(cs), [w0] "v"(w0), [w1] "v"(w1), [w2] "v"(w2), [w3] "v"(w3),
          [wn0] "v"(wn0), [wn1] "v"(wn1), [wn2] "v"(wn2), [wn3] "v"(wn3),
          [i0] "v"(i0), [i1] "v"(i1), [i2] "v"(i2), [i3] "v"(i3),
          [bbn] "v"(bbn), [ka] "v"(ka), [kb] "v"(kb));
    cs = cn;   // rename, no mov
}

// Layer-split wave specialization (R8/R14 skeleton):
//   wave 0 = "A": layer 0 for 4 chains; wave 1 = "B": layer 1, 1 segment behind.
// ring[32][4][4] (2 KB), barrier per 16 steps, parity halves disjoint.
// 1024 blocks x 2 waves = 2048 waves = 2 waves/SIMD.
__global__ __launch_bounds__(128, 2) void lstm2_split(
    const float* __restrict__ x,
    const float* __restrict__ Wih0, const float* __restrict__ Whh0,
    const float* __restrict__ bih0, const float* __restrict__ bhh0,
    const float* __restrict__ Wih1, const float* __restrict__ Whh1,
    const float* __restrict__ b_ih1, const float* __restrict__ b_hh1,
    float* __restrict__ out)
{
    __shared__ float ring[32][4][4];   // [slot][chain-in-block][unit]

    const int wv    = threadIdx.x >> 6;     // 0 = A (layer0), 1 = B (layer1)
    const int lane  = threadIdx.x & 63;
    const int cpos  = lane >> 4;            // chain-in-block 0..3
    const int g16   = lane & 15;
    const int u     = g16 >> 2;             // hidden unit (quad)
    const int r     = g16 & 3;              // role 0=i 1=f 2=g 3=o
    const int row   = r * 4 + u;            // PyTorch gate-row
    const int chain = blockIdx.x * 4 + cpos;
    const bool isA  = (wv == 0);

    // Fold -log2e (sigmoid) / -2log2e (tanh row) into weights & bias.
    // Input dots natural order (in-lane operands); recurrent dots u-relative,
    // matching the asm DPP order: w0<->u, w1<->u^1(RHM), w2<->u^2(ROR8), w3<->u^3(MIR).
    const float srow = (r == 2) ? (-2.0f * LOG2E) : (-LOG2E);
    float win[4], whh[4], bb;
    if (isA) {
#pragma unroll
        for (int d = 0; d < 4; ++d) {
            win[d] = Wih0[row * 4 + d]       * srow;
            whh[d] = Whh0[row * 4 + (u ^ d)] * srow;
        }
        bb = (bih0[row] + bhh0[row]) * srow;
    } else {
#pragma unroll
        for (int d = 0; d < 4; ++d) {
            win[d] = Wih1[row * 4 + d]       * srow;
            whh[d] = Whh1[row * 4 + (u ^ d)] * srow;
        }
        bb = (b_ih1[row] + b_hh1[row]) * srow;
    }
    // g-row activation folds the cell-tanh arg scale: cs tracks -2log2e * c.
    const float csc = -2.0f * LOG2E;
    const float ka = (r == 2) ? 2.0f * csc : 1.0f;
    const float kb = (r == 2) ? -csc       : 0.0f;

    const char* __restrict__ xb = (const char*)x;
    char* __restrict__ ob = (char*)out;

    float h = 0.f, cs = 0.f, acc, accn;

    if (isA) {
        // ---------------- layer-0 wave ----------------
        const unsigned xhome = (unsigned)chain * 16u;
        const unsigned XCL   = xhome + 2047u * 65536u;
        float4 xbuf[8];
        unsigned xoff = xhome;
#pragma unroll
        for (int i = 0; i < 8; ++i) {           // prologue: x(0..7) in flight
            xbuf[i] = *(const float4*)(xb + xoff);
            xoff += 65536u;
        }
        // acc for step 0 (rolls forward inside the asm thereafter; the i=15
        // accn is computed from xbuf[0]=x(next seg first) -> valid across segs)
        acc = fmaf(win[0], xbuf[0].x, fmaf(win[1], xbuf[0].y,
              fmaf(win[2], xbuf[0].z, fmaf(win[3], xbuf[0].w, bb))));
        for (int seg = 0; seg <= NSEG; ++seg) {
            __syncthreads();
            if (seg < NSEG) {
                float (*slot)[4] = ring[(seg & 1) * K_SEG];
                if (seg < NSEG - 1) {
                    // unclamped main path
#pragma unroll
                    for (int i = 0; i < K_SEG; ++i) {
                        const float4 xn = xbuf[(i + 1) & 7];   // step t+1 input
                        xbuf[i & 7] = *(const float4*)(xb + xoff);
                        xoff += 65536u;
                        cell_pipe(acc, accn, h, cs,
                                  whh[0], whh[1], whh[2], whh[3],
                                  win[0], win[1], win[2], win[3],
                                  xn.x, xn.y, xn.z, xn.w, bb, ka, kb);
                        if (r == 0) slot[i * 4 + cpos][u] = h;
                        acc = accn;
                    }
                } else {
                    // final segment: clamp refills at the sequence end
#pragma unroll
                    for (int i = 0; i < K_SEG; ++i) {
                        const float4 xn = xbuf[(i + 1) & 7];
                        unsigned off = (xoff < XCL) ? xoff : XCL;
                        xbuf[i & 7] = *(const float4*)(xb + off);
                        xoff += 65536u;
                        cell_pipe(acc, accn, h, cs,
                                  whh[0], whh[1], whh[2], whh[3],
                                  win[0], win[1], win[2], win[3],
                                  xn.x, xn.y, xn.z, xn.w, bb, ka, kb);
                        if (r == 0) slot[i * 4 + cpos][u] = h;
                        acc = accn;
                    }
                }
            }
        }
    } else {
        // ---------------- layer-1 wave ----------------
        unsigned ooff = (unsigned)(chain * 16 + u * 4);   // out[0][chain][u]
        for (int seg = 0; seg <= NSEG; ++seg) {
            __syncthreads();
            if (seg > 0) {
                const float (*slot)[4] = ring[((seg - 1) & 1) * K_SEG];
                float4 hr[16];
#pragma unroll
                for (int s = 0; s < 16; ++s)
                    hr[s] = *(const float4*)&slot[s * 4 + cpos][0];
                // first-step dot in C (last iter's accn is discarded per seg)
                acc = fmaf(win[0], hr[0].x, fmaf(win[1], hr[0].y,
                      fmaf(win[2], hr[0].z, fmaf(win[3], hr[0].w, bb))));
#pragma unroll
                for (int i = 0; i < K_SEG; ++i) {
                    const float4 xn = hr[(i < 15) ? (i + 1) : 15]; // 15: dummy
                    cell_pipe(acc, accn, h, cs,
                              whh[0], whh[1], whh[2], whh[3],
                              win[0], win[1], win[2], win[3],
                              xn.x, xn.y, xn.z, xn.w, bb, ka, kb);
                    if (r == 0) *(float*)(ob + ooff) = h;
                    ooff += 65536u;
                    acc = accn;
                }
            }
        }
    }
}

extern "C" void kernel_launch(void* const* d_in, const int* in_sizes, int n_in,
                              void* d_out, int out_size, void* d_ws, size_t ws_size,
                              hipStream_t stream) {
    const float* x    = (const float*)d_in[0];
    const float* Wih0 = (const float*)d_in[1];
    const float* Whh0 = (const float*)d_in[2];
    const float* bih0 = (const float*)d_in[3];
    const float* bhh0 = (const float*)d_in[4];
    const float* Wih1 = (const float*)d_in[5];
    const float* Whh1 = (const float*)d_in[6];
    const float* bih1 = (const float*)d_in[7];
    const float* bhh1 = (const float*)d_in[8];
    float* out = (float*)d_out;

    // 1024 blocks x 2 waves (1 A + 1 B) = 2048 waves = 2 waves/SIMD
    dim3 grid(1024), block(128);
    hipLaunchKernelGGL(lstm2_split, grid, block, 0, stream,
                       x, Wih0, Whh0, bih0, bhh0, Wih1, Whh1, bih1, bhh1, out);
}

// Round 16
// 246.609 us; speedup vs baseline: 1.0190x; 1.0190x over previous
//
#include <hip/hip_runtime.h>

#define SEQ_T   2048
#define BATCH_N 4096
#define LOG2E   1.4426950408889634f
#define K_SEG   16
#define NSEG    (SEQ_T / K_SEG)   // 128 segments

// LSTM cell step, hand-scheduled, DPP-fused operands (VOP2 src0-DPP).
// 16-lane chain group, UNIT-MAJOR lane = 4u + r; h, cs quad-uniform.
// Recurrent dot as TWO parallel accumulators (chain -8 cyc vs serial):
//   q   = w1*h_{u^1} (mul RHM) ; q += w3*h_{u^3} (fmac MIR)
//   acc += w2*h_{u^2} (fmac ROR8) ; acc += w0*h (plain) ; acc += q
// Gate gather fused via quad_perm (only g needs a real mov).
// Hazard audit (model validated R13->R14):
//  (a) trans write -> consumer: 1 wait  => s_nop 0 after exp/rcp.
//  (b) VALU write -> DPP read of same VGPR: 2 waits => entry s_nop 3 covers
//      the seam (h written by prev cell's final v_mul; caller instrs add
//      distance); s_nop 1 before the a->quad_perm reads.
//  (c) SALU EXEC write -> DPP: 5 waits => entry s_nop 3 + caller instrs.
//  q/acc/t plain reads are HW-interlocked.
__device__ __forceinline__ void cell_asm(float& acc, float& h, float& cs,
                                         float w0, float w1, float w2, float w3,
                                         float ka, float kb) {
    float t, a, gv, cn, hn, q;
    asm("s_nop 3\n\t"                                   // (b)/(c) seam for DPP h
        "v_mul_f32 %[q], %[h], %[w1] row_half_mirror row_mask:0xf bank_mask:0xf\n\t"
        "v_fmac_f32 %[acc], %[h], %[w2] row_ror:8 row_mask:0xf bank_mask:0xf\n\t"
        "v_fmac_f32 %[q], %[h], %[w3] row_mirror row_mask:0xf bank_mask:0xf\n\t"
        "v_fmac_f32 %[acc], %[h], %[w0]\n\t"            // plain h (interlocked)
        "v_add_f32 %[acc], %[acc], %[q]\n\t"
        "v_exp_f32 %[t], %[acc]\n\t"
        "s_nop 0\n\t"                                   // (a)
        "v_add_f32 %[t], 1.0, %[t]\n\t"
        "v_rcp_f32 %[t], %[t]\n\t"
        "s_nop 0\n\t"                                   // (a)
        "v_fma_f32 %[a], %[ka], %[t], %[kb]\n\t"
        "s_nop 1\n\t"                                   // (b) a -> quad_perm
        "v_mov_b32 %[gv], %[a] quad_perm:[2,2,2,2] row_mask:0xf bank_mask:0xf\n\t"
        "v_mul_f32 %[cn], %[a], %[gv] quad_perm:[0,0,0,0] row_mask:0xf bank_mask:0xf\n\t"
        "v_fmac_f32 %[cn], %[a], %[cs] quad_perm:[1,1,1,1] row_mask:0xf bank_mask:0xf\n\t"
        "v_exp_f32 %[t], %[cn]\n\t"
        "s_nop 0\n\t"                                   // (a)
        "v_add_f32 %[t], 1.0, %[t]\n\t"
        "v_rcp_f32 %[t], %[t]\n\t"
        "s_nop 0\n\t"                                   // (a)
        "v_fma_f32 %[hn], 2.0, %[t], -1.0\n\t"
        "v_mul_f32 %[h], %[a], %[hn] quad_perm:[3,3,3,3] row_mask:0xf bank_mask:0xf\n\t"
        : [acc] "+v"(acc), [h] "+v"(h),
          [t] "=&v"(t), [a] "=&v"(a), [gv] "=&v"(gv),
          [cn] "=&v"(cn), [hn] "=&v"(hn), [q] "=&v"(q)
        : [cs] "v"(cs), [w0] "v"(w0), [w1] "v"(w1), [w2] "v"(w2), [w3] "v"(w3),
          [ka] "v"(ka), [kb] "v"(kb));
    cs = cn;   // register rename, no mov emitted
}

// Layer-split wave specialization (R8/R14 skeleton, unchanged structure):
//   wave 0 = "A": layer 0 for 4 chains (16 lanes/chain, UNIT-MAJOR 4u+r)
//   wave 1 = "B": layer 1, same chains, one 16-step segment behind
// Handoff ring[32 slots][4 chains][4 units] (2 KB). A writes h0 (r==0 lanes);
// B reads ds_read_b128 -> all 4 h0 components IN-LANE. Barrier every 16
// steps; segment parity gives disjoint ring halves.
// 1024 blocks x 2 waves = 2048 waves = 2 waves/SIMD.
__global__ __launch_bounds__(128, 2) void lstm2_split(
    const float* __restrict__ x,
    const float* __restrict__ Wih0, const float* __restrict__ Whh0,
    const float* __restrict__ bih0, const float* __restrict__ bhh0,
    const float* __restrict__ Wih1, const float* __restrict__ Whh1,
    const float* __restrict__ bih1, const float* __restrict__ bhh1,
    float* __restrict__ out)
{
    __shared__ float ring[32][4][4];   // [slot][chain-in-block][unit]

    const int wv    = threadIdx.x >> 6;     // 0 = A (layer0), 1 = B (layer1)
    const int lane  = threadIdx.x & 63;
    const int cpos  = lane >> 4;            // chain-in-block 0..3
    const int g16   = lane & 15;
    const int u     = g16 >> 2;             // hidden unit (quad)
    const int r     = g16 & 3;              // role 0=i 1=f 2=g 3=o
    const int row   = r * 4 + u;            // PyTorch gate-row
    const int chain = blockIdx.x * 4 + cpos;
    const bool isA  = (wv == 0);

    // Fold -log2e (sigmoid) / -2log2e (tanh row) into weights & bias.
    // Input dots natural order (x / LDS-h0 in-lane); recurrent dots
    // u-relative order matching the asm DPP sequence:
    //   w0 <-> u (plain), w1 <-> u^1 (RHM), w2 <-> u^2 (ROR8), w3 <-> u^3 (MIR).
    const float srow = (r == 2) ? (-2.0f * LOG2E) : (-LOG2E);
    float win[4], whh[4], bb;
    if (isA) {
#pragma unroll
        for (int d = 0; d < 4; ++d) {
            win[d] = Wih0[row * 4 + d]       * srow;
            whh[d] = Whh0[row * 4 + (u ^ d)] * srow;
        }
        bb = (bih0[row] + bhh0[row]) * srow;
    } else {
#pragma unroll
        for (int d = 0; d < 4; ++d) {
            win[d] = Wih1[row * 4 + d]       * srow;
            whh[d] = Whh1[row * 4 + (u ^ d)] * srow;
        }
        bb = (bih1[row] + bhh1[row]) * srow;
    }
    // g-row activation folds the cell-tanh arg scale: cs tracks -2log2e * c.
    const float csc = -2.0f * LOG2E;
    const float ka = (r == 2) ? 2.0f * csc : 1.0f;
    const float kb = (r == 2) ? -csc       : 0.0f;

    const char* __restrict__ xb = (const char*)x;
    char* __restrict__ ob = (char*)out;

    float h = 0.f, cs = 0.f;

    if (isA) {
        // ---------------- layer-0 wave ----------------
        const unsigned xhome = (unsigned)chain * 16u;
        const unsigned XCL   = xhome + 2047u * 65536u;
        float4 xbuf[8];
        unsigned xoff = xhome;
#pragma unroll
        for (int i = 0; i < 8; ++i) {           // prologue: x(0..7) in flight
            xbuf[i] = *(const float4*)(xb + xoff);
            xoff += 65536u;
        }
        for (int seg = 0; seg <= NSEG; ++seg) {
            __syncthreads();
            if (seg < NSEG) {
                float (*slot)[4] = ring[(seg & 1) * K_SEG];
                if (seg < NSEG - 1) {
                    // unclamped main path: refill max = 16*seg+23 < 2048
#pragma unroll
                    for (int i = 0; i < K_SEG; ++i) {
                        const float4 xv = xbuf[i & 7];
                        xbuf[i & 7] = *(const float4*)(xb + xoff);
                        xoff += 65536u;
                        float acc = fmaf(win[0], xv.x, fmaf(win[1], xv.y,
                                    fmaf(win[2], xv.z, fmaf(win[3], xv.w, bb))));
                        cell_asm(acc, h, cs, whh[0], whh[1], whh[2], whh[3], ka, kb);
                        if (r == 0) slot[i * 4 + cpos][u] = h;
                    }
                } else {
                    // final segment: clamp refills at the sequence end
#pragma unroll
                    for (int i = 0; i < K_SEG; ++i) {
                        const float4 xv = xbuf[i & 7];
                        unsigned off = (xoff < XCL) ? xoff : XCL;
                        xbuf[i & 7] = *(const float4*)(xb + off);
                        xoff += 65536u;
                        float acc = fmaf(win[0], xv.x, fmaf(win[1], xv.y,
                                    fmaf(win[2], xv.z, fmaf(win[3], xv.w, bb))));
                        cell_asm(acc, h, cs, whh[0], whh[1], whh[2], whh[3], ka, kb);
                        if (r == 0) slot[i * 4 + cpos][u] = h;
                    }
                }
            }
        }
    } else {
        // ---------------- layer-1 wave ----------------
        unsigned ooff = (unsigned)(chain * 16 + u * 4);   // out[0][chain][u]
        for (int seg = 0; seg <= NSEG; ++seg) {
            __syncthreads();
            if (seg > 0) {
                const float (*slot)[4] = ring[((seg - 1) & 1) * K_SEG];
                float4 hr[8];
#pragma unroll
                for (int hf = 0; hf < 2; ++hf) {
#pragma unroll
                    for (int s = 0; s < 8; ++s)
                        hr[s] = *(const float4*)&slot[(hf * 8 + s) * 4 + cpos][0];
#pragma unroll
                    for (int i = 0; i < 8; ++i) {
                        const float4 X = hr[i];
                        float acc = fmaf(win[0], X.x, fmaf(win[1], X.y,
                                    fmaf(win[2], X.z, fmaf(win[3], X.w, bb))));
                        cell_asm(acc, h, cs, whh[0], whh[1], whh[2], whh[3], ka, kb);
                        if (r == 0) *(float*)(ob + ooff) = h;
                        ooff += 65536u;
                    }
                }
            }
        }
    }
}

extern "C" void kernel_launch(void* const* d_in, const int* in_sizes, int n_in,
                              void* d_out, int out_size, void* d_ws, size_t ws_size,
                              hipStream_t stream) {
    const float* x    = (const float*)d_in[0];
    const float* Wih0 = (const float*)d_in[1];
    const float* Whh0 = (const float*)d_in[2];
    const float* bih0 = (const float*)d_in[3];
    const float* bhh0 = (const float*)d_in[4];
    const float* Wih1 = (const float*)d_in[5];
    const float* Whh1 = (const float*)d_in[6];
    const float* bih1 = (const float*)d_in[7];
    const float* bhh1 = (const float*)d_in[8];
    float* out = (float*)d_out;

    // 1024 blocks x 2 waves (1 A + 1 B) = 2048 waves = 2 waves/SIMD
    dim3 grid(1024), block(128);
    hipLaunchKernelGGL(lstm2_split, grid, block, 0, stream,
                       x, Wih0, Whh0, bih0, bhh0, Wih1, Whh1, bih1, bhh1, out);
}

// Round 17
// 231.308 us; speedup vs baseline: 1.0864x; 1.0662x over previous
//
#include <hip/hip_runtime.h>

#define SEQ_T   2048
#define BATCH_N 4096
#define LOG2E   1.4426950408889634f
#define K_SEG   16
#define NSEG    (SEQ_T / K_SEG)   // 128 segments

// One LSTM cell step, hand-scheduled, DPP-fused operands (VOP2 src0-DPP).
// 16-lane chain group, UNIT-MAJOR lane = 4u + r; h, cs are quad-uniform.
// Recurrent dot taps h's quad-mirrors directly (w_d pairs with h_{u^d}):
//   w0: plain, w1: row_half_mirror (u^1), w2: row_ror:8 (u^2), w3: row_mirror (u^3)
// Gate gather fused into consumers via quad_perm (only g needs a real mov).
//
// COMPLETE gfx9 manual-wait-state audit (compiler does this for its own code,
// asm must self-insert):
//  (a) trans op (v_exp/v_rcp) write -> ANY consumer: 1 wait  => s_nop 0 after
//      every v_exp/v_rcp whose result is read next.
//  (b) VALU write -> DPP read of that VGPR: 2 waits => s_nop 1 before the
//      quad_perm reads of `a`; s_nop 3 at entry covers the seam (h written by
//      the previous cell's final v_mul).
//  (c) SALU EXEC write -> DPP: 5 waits => entry gap = >=1 caller instr +
//      1 fmac + 4 nop cycles >= 5 since any saveexec/restore in the caller.
//  Plain (non-DPP) VALU->VALU reads are HW-interlocked.
__device__ __forceinline__ void cell_asm(float& acc, float& h, float& cs,
                                         float w0, float w1, float w2, float w3,
                                         float ka, float kb) {
    float t, a, gv, cn, hn;
    asm("v_fmac_f32 %[acc], %[h], %[w0]\n\t"            // plain h (interlocked)
        "s_nop 3\n\t"                                   // (b)/(c) for DPP h reads
        "v_fmac_f32 %[acc], %[h], %[w1] row_half_mirror row_mask:0xf bank_mask:0xf\n\t"
        "v_fmac_f32 %[acc], %[h], %[w2] row_ror:8 row_mask:0xf bank_mask:0xf\n\t"
        "v_fmac_f32 %[acc], %[h], %[w3] row_mirror row_mask:0xf bank_mask:0xf\n\t"
        "v_exp_f32 %[t], %[acc]\n\t"
        "s_nop 0\n\t"                                   // (a)
        "v_add_f32 %[t], 1.0, %[t]\n\t"
        "v_rcp_f32 %[t], %[t]\n\t"
        "s_nop 0\n\t"                                   // (a)
        "v_fma_f32 %[a], %[ka], %[t], %[kb]\n\t"
        "s_nop 1\n\t"                                   // (b) a -> quad_perm
        "v_mov_b32 %[gv], %[a] quad_perm:[2,2,2,2] row_mask:0xf bank_mask:0xf\n\t"
        "v_mul_f32 %[cn], %[a], %[gv] quad_perm:[0,0,0,0] row_mask:0xf bank_mask:0xf\n\t"
        "v_fmac_f32 %[cn], %[a], %[cs] quad_perm:[1,1,1,1] row_mask:0xf bank_mask:0xf\n\t"
        "v_exp_f32 %[t], %[cn]\n\t"
        "s_nop 0\n\t"                                   // (a)
        "v_add_f32 %[t], 1.0, %[t]\n\t"
        "v_rcp_f32 %[t], %[t]\n\t"
        "s_nop 0\n\t"                                   // (a)
        "v_fma_f32 %[hn], 2.0, %[t], -1.0\n\t"
        "v_mul_f32 %[h], %[a], %[hn] quad_perm:[3,3,3,3] row_mask:0xf bank_mask:0xf\n\t"
        : [acc] "+v"(acc), [h] "+v"(h),
          [t] "=&v"(t), [a] "=&v"(a), [gv] "=&v"(gv),
          [cn] "=&v"(cn), [hn] "=&v"(hn)
        : [cs] "v"(cs), [w0] "v"(w0), [w1] "v"(w1), [w2] "v"(w2), [w3] "v"(w3),
          [ka] "v"(ka), [kb] "v"(kb));
    cs = cn;   // register rename, no mov emitted
}

// Layer-split wave specialization (R8 skeleton, unchanged structure):
//   wave 0 = "A": layer 0 for 4 chains (16 lanes/chain, UNIT-MAJOR 4u+r)
//   wave 1 = "B": layer 1, same chains, one 16-step segment behind
// Handoff ring[32 slots][4 chains][4 units] (2 KB). A writes h0 (r==0 lanes);
// B reads ds_read_b128 -> all 4 h0 components IN-LANE. Barrier every 16
// steps; segment parity gives disjoint ring halves.
// 1024 blocks x 2 waves = 2048 waves = 2 waves/SIMD.
__global__ __launch_bounds__(128, 2) void lstm2_split(
    const float* __restrict__ x,
    const float* __restrict__ Wih0, const float* __restrict__ Whh0,
    const float* __restrict__ bih0, const float* __restrict__ bhh0,
    const float* __restrict__ Wih1, const float* __restrict__ Whh1,
    const float* __restrict__ bih1, const float* __restrict__ bhh1,
    float* __restrict__ out)
{
    __shared__ float ring[32][4][4];   // [slot][chain-in-block][unit]

    const int wv    = threadIdx.x >> 6;     // 0 = A (layer0), 1 = B (layer1)
    const int lane  = threadIdx.x & 63;
    const int cpos  = lane >> 4;            // chain-in-block 0..3
    const int g16   = lane & 15;
    const int u     = g16 >> 2;             // hidden unit (quad)
    const int r     = g16 & 3;              // role 0=i 1=f 2=g 3=o
    const int row   = r * 4 + u;            // PyTorch gate-row
    const int chain = blockIdx.x * 4 + cpos;
    const bool isA  = (wv == 0);

    // Fold -log2e (sigmoid) / -2log2e (tanh row) into weights & bias.
    // Input dots natural order (x / LDS-h0 in-lane); recurrent dots
    // u-relative order matching the asm DPP sequence:
    //   w0 <-> u, w1 <-> u^1 (RHM), w2 <-> u^2 (ROR8), w3 <-> u^3 (MIR).
    const float srow = (r == 2) ? (-2.0f * LOG2E) : (-LOG2E);
    float win[4], whh[4], bb;
    if (isA) {
#pragma unroll
        for (int d = 0; d < 4; ++d) {
            win[d] = Wih0[row * 4 + d]       * srow;
            whh[d] = Whh0[row * 4 + (u ^ d)] * srow;
        }
        bb = (bih0[row] + bhh0[row]) * srow;
    } else {
#pragma unroll
        for (int d = 0; d < 4; ++d) {
            win[d] = Wih1[row * 4 + d]       * srow;
            whh[d] = Whh1[row * 4 + (u ^ d)] * srow;
        }
        bb = (bih1[row] + bhh1[row]) * srow;
    }
    // g-row activation folds the cell-tanh arg scale: cs tracks -2log2e * c.
    const float csc = -2.0f * LOG2E;
    const float ka = (r == 2) ? 2.0f * csc : 1.0f;
    const float kb = (r == 2) ? -csc       : 0.0f;

    const char* __restrict__ xb = (const char*)x;
    char* __restrict__ ob = (char*)out;

    float h = 0.f, cs = 0.f;

    if (isA) {
        // ---------------- layer-0 wave ----------------
        const unsigned xhome = (unsigned)chain * 16u;
        const unsigned XCL   = xhome + 2047u * 65536u;
        float4 xbuf[8];
        unsigned xoff = xhome;
#pragma unroll
        for (int i = 0; i < 8; ++i) {           // prologue: x(0..7) in flight
            xbuf[i] = *(const float4*)(xb + xoff);
            xoff += 65536u;
        }
        for (int seg = 0; seg <= NSEG; ++seg) {
            __syncthreads();
            if (seg < NSEG) {
                float (*slot)[4] = ring[(seg & 1) * K_SEG];
#pragma unroll
                for (int i = 0; i < K_SEG; ++i) {
                    const float4 xv = xbuf[i & 7];
                    unsigned off = (xoff < XCL) ? xoff : XCL;   // clamp tail
                    xbuf[i & 7] = *(const float4*)(xb + off);
                    xoff += 65536u;
                    float acc = fmaf(win[0], xv.x, fmaf(win[1], xv.y,
                                fmaf(win[2], xv.z, fmaf(win[3], xv.w, bb))));
                    cell_asm(acc, h, cs, whh[0], whh[1], whh[2], whh[3], ka, kb);
                    if (r == 0) slot[i * 4 + cpos][u] = h;
                }
            }
        }
    } else {
        // ---------------- layer-1 wave ----------------
        unsigned ooff = (unsigned)(chain * 16 + u * 4);   // out[0][chain][u]
        for (int seg = 0; seg <= NSEG; ++seg) {
            __syncthreads();
            if (seg > 0) {
                const float (*slot)[4] = ring[((seg - 1) & 1) * K_SEG];
                float4 hr[8];
#pragma unroll
                for (int hf = 0; hf < 2; ++hf) {
#pragma unroll
                    for (int s = 0; s < 8; ++s)
                        hr[s] = *(const float4*)&slot[(hf * 8 + s) * 4 + cpos][0];
#pragma unroll
                    for (int i = 0; i < 8; ++i) {
                        const float4 X = hr[i];
                        float acc = fmaf(win[0], X.x, fmaf(win[1], X.y,
                                    fmaf(win[2], X.z, fmaf(win[3], X.w, bb))));
                        cell_asm(acc, h, cs, whh[0], whh[1], whh[2], whh[3], ka, kb);
                        if (r == 0) *(float*)(ob + ooff) = h;
                        ooff += 65536u;
                    }
                }
            }
        }
    }
}

extern "C" void kernel_launch(void* const* d_in, const int* in_sizes, int n_in,
                              void* d_out, int out_size, void* d_ws, size_t ws_size,
                              hipStream_t stream) {
    const float* x    = (const float*)d_in[0];
    const float* Wih0 = (const float*)d_in[1];
    const float* Whh0 = (const float*)d_in[2];
    const float* bih0 = (const float*)d_in[3];
    const float* bhh0 = (const float*)d_in[4];
    const float* Wih1 = (const float*)d_in[5];
    const float* Whh1 = (const float*)d_in[6];
    const float* bih1 = (const float*)d_in[7];
    const float* bhh1 = (const float*)d_in[8];
    float* out = (float*)d_out;

    // 1024 blocks x 2 waves (1 A + 1 B) = 2048 waves = 2 waves/SIMD
    dim3 grid(1024), block(128);
    hipLaunchKernelGGL(lstm2_split, grid, block, 0, stream,
                       x, Wih0, Whh0, bih0, bhh0, Wih1, Whh1, bih1, bhh1, out);
}